// Round 1
// baseline (388.128 us; speedup 1.0000x reference)
//
#include <hip/hip_runtime.h>
#include <hip/hip_bf16.h>

// out[b,s,o] = scale[o] * dot(x[b,s,:], w_eff[o,:])
//   w_eff = weight + 2.0*(b_w @ a_w);  scale[o] = magnitude[o]/||w_eff[o,:]||
// Phase 1: prep builds w_eff bf16 + scale fp32                 (~10us)
// Phase 2: FUSED bf16 MFMA GEMM reading x fp32 directly:
//          A reg-staged (global float4 -> cvt bf16 -> ds_write),
//          B via global_load_lds width=16 DMA,
//          double-buffered LDS, single barrier per K-step (T3 2-phase),
//          loads issued before MFMA, LDS writes after (T14).
// The former x_to_bf16 pass (192 MB streamed) is eliminated.

typedef __bf16 bf16x8 __attribute__((ext_vector_type(8)));
typedef float  f32x4  __attribute__((ext_vector_type(4)));

#define D_IN  1024
#define D_OUT 1024
#define M_TOT 32768
#define BM 128
#define BN 128
#define BK 32
#define NKT (D_IN / BK)

__device__ __forceinline__ void gl_lds16(const __bf16* g, __bf16* l) {
    // HBM -> LDS DMA, 16B per lane; LDS dest = wave-uniform base + lane*16.
    __builtin_amdgcn_global_load_lds(
        (const __attribute__((address_space(1))) void*)g,
        (__attribute__((address_space(3))) void*)l,
        16, 0, 0);
}

__device__ __forceinline__ void cvt_store16(__bf16* dst, float4 v0, float4 v1,
                                            float4 v2, float4 v3) {
    bf16x8 p0 = { (__bf16)v0.x, (__bf16)v0.y, (__bf16)v0.z, (__bf16)v0.w,
                  (__bf16)v1.x, (__bf16)v1.y, (__bf16)v1.z, (__bf16)v1.w };
    bf16x8 p1 = { (__bf16)v2.x, (__bf16)v2.y, (__bf16)v2.z, (__bf16)v2.w,
                  (__bf16)v3.x, (__bf16)v3.y, (__bf16)v3.z, (__bf16)v3.w };
    *(bf16x8*)(dst)     = p0;
    *(bf16x8*)(dst + 8) = p1;
}

__global__ void dora_prep(const float* __restrict__ w,
                          const float* __restrict__ a_w,
                          const float* __restrict__ b_w,
                          const float* __restrict__ mag,
                          __bf16* __restrict__ wb,
                          float* __restrict__ scale) {
    const int o = blockIdx.x;
    const int t = threadIdx.x;

    float bw[16];
#pragma unroll
    for (int r = 0; r < 16; ++r) bw[r] = b_w[o * 16 + r];

    float ss = 0.f;
#pragma unroll
    for (int i = 0; i < 4; ++i) {
        const int k = t + i * 256;
        float dot = 0.f;
#pragma unroll
        for (int r = 0; r < 16; ++r) dot = fmaf(bw[r], a_w[r * D_IN + k], dot);
        const float acc = fmaf(2.0f, dot, w[o * D_IN + k]);
        wb[o * D_IN + k] = (__bf16)acc;
        ss = fmaf(acc, acc, ss);
    }
#pragma unroll
    for (int off = 32; off; off >>= 1) ss += __shfl_down(ss, off, 64);
    __shared__ float wsum[4];
    if ((t & 63) == 0) wsum[t >> 6] = ss;
    __syncthreads();
    if (t == 0) {
        const float tot = wsum[0] + wsum[1] + wsum[2] + wsum[3];
        scale[o] = mag[o] / sqrtf(tot);
    }
}

__global__ __launch_bounds__(256) void dora_gemm(const float* __restrict__ x,
                                                 const __bf16* __restrict__ wb,
                                                 const float* __restrict__ scale,
                                                 float* __restrict__ out) {
    // Double-buffered tiles. As/Bs row-major [128][32] bf16 (8 KB each buf).
    // Bs must stay lane-contiguous (global_load_lds dest); As is reg-written.
    __shared__ __bf16 As[2][BM * BK];
    __shared__ __bf16 Bs[2][BN * BK];

    const int bx = blockIdx.x;
    // XCD-aware swizzle: xcd = bx&7; 8 bn-siblings sharing one A panel land
    // consecutively on the SAME XCD's L2 -> fp32 A re-reads are L2 hits.
    const int xcd = bx & 7;
    const int l   = bx >> 3;
    const int bm  = (xcd * 32 + (l >> 3)) * BM;
    const int bn  = (l & 7) * BN;

    const int t    = threadIdx.x;
    const int lane = t & 63;
    const int wave = t >> 6;
    const int wm = (wave & 1) * 64;
    const int wn = (wave >> 1) * 64;
    const int lm = lane & 15;
    const int lq = lane >> 4;

    // A staging (reg path): thread t owns row t>>1, 16-float half (t&1).
    const int arow = t >> 1;
    const int acol = (t & 1) * 16;
    const float* ag = x + (size_t)(bm + arow) * D_IN + acol;
    const int aoff  = arow * BK + acol;   // element offset inside an As buffer

    // B staging (DMA path): wave stages 2x 1KB chunks, lane i -> row i>>2,
    // 16B col chunk i&3; LDS byte offset 16*i (lane-contiguous).
    const int srow0 = wave * 32 + (lane >> 2);
    const int scol  = (lane & 3) * 8;
    const __bf16* bg0 = wb + (size_t)(bn + srow0) * D_IN + scol;
    const __bf16* bg1 = bg0 + 16 * D_IN;
    const int boff0 = wave * 1024;
    const int boff1 = wave * 1024 + 512;

    f32x4 acc[4][4] = {};

    // ---- prologue: stage K-tile 0 into buffer 0 ----
    float4 v0 = *(const float4*)(ag);
    float4 v1 = *(const float4*)(ag + 4);
    float4 v2 = *(const float4*)(ag + 8);
    float4 v3 = *(const float4*)(ag + 12);
    gl_lds16(bg0, &Bs[0][boff0]);
    gl_lds16(bg1, &Bs[0][boff1]);
    cvt_store16(&As[0][aoff], v0, v1, v2, v3);
    __syncthreads();   // compiler emits vmcnt(0) lgkmcnt(0) drain here

    int cur = 0;
    for (int kt = 0; kt < NKT; ++kt) {
        const int nxt = cur ^ 1;
        const bool has_next = (kt + 1) < NKT;

        // 1) issue next-tile loads FIRST: HBM latency hides under the MFMAs.
        if (has_next) {
            const float* agn = ag + (kt + 1) * BK;
            v0 = *(const float4*)(agn);
            v1 = *(const float4*)(agn + 4);
            v2 = *(const float4*)(agn + 8);
            v3 = *(const float4*)(agn + 12);
            const __bf16* bgn0 = bg0 + (kt + 1) * BK;
            const __bf16* bgn1 = bg1 + (kt + 1) * BK;
            gl_lds16(bgn0, &Bs[nxt][boff0]);
            gl_lds16(bgn1, &Bs[nxt][boff1]);
        }

        // 2) compute on buffer `cur`
        const __bf16* Ar = As[cur];
        const __bf16* Br = Bs[cur];
        bf16x8 af[4], bfr[4];
#pragma unroll
        for (int i = 0; i < 4; ++i)
            af[i] = *(const bf16x8*)(&Ar[(wm + i * 16 + lm) * BK + lq * 8]);
#pragma unroll
        for (int i = 0; i < 4; ++i)
            bfr[i] = *(const bf16x8*)(&Br[(wn + i * 16 + lm) * BK + lq * 8]);

#pragma unroll
        for (int i = 0; i < 4; ++i)
#pragma unroll
            for (int j = 0; j < 4; ++j)
                acc[i][j] = __builtin_amdgcn_mfma_f32_16x16x32_bf16(af[i], bfr[j], acc[i][j], 0, 0, 0);

        // 3) convert + LDS-write the prefetched A tile (waits only on the
        //    global loads issued in step 1; writes go to the OTHER buffer).
        if (has_next)
            cvt_store16(&As[nxt][aoff], v0, v1, v2, v3);

        // 4) one barrier per K-step: next buffer ready (incl. B DMA drain),
        //    and everyone is done reading `cur` before it gets overwritten.
        __syncthreads();
        cur = nxt;
    }

    // Epilogue: C/D map col = lane&15 (n), row = (lane>>4)*4 + reg (m)
#pragma unroll
    for (int j = 0; j < 4; ++j) {
        const int n = bn + wn + j * 16 + lm;
        const float sc = scale[n];
#pragma unroll
        for (int i = 0; i < 4; ++i) {
            const int m = bm + wm + i * 16 + lq * 4;
#pragma unroll
            for (int r = 0; r < 4; ++r) {
                out[(size_t)(m + r) * D_OUT + n] = acc[i][j][r] * sc;
            }
        }
    }
}

extern "C" void kernel_launch(void* const* d_in, const int* in_sizes, int n_in,
                              void* d_out, int out_size, void* d_ws, size_t ws_size,
                              hipStream_t stream) {
    const float* x    = (const float*)d_in[0];   // [4,8192,1024] fp32
    const float* w    = (const float*)d_in[1];   // [1024,1024]
    const float* a_w  = (const float*)d_in[2];   // [16,1024]
    const float* b_w  = (const float*)d_in[3];   // [1024,16]
    const float* mag  = (const float*)d_in[4];   // [1,1024]
    float* out = (float*)d_out;                  // [4,8192,1024] fp32

    __bf16* wb   = (__bf16*)d_ws;                                   // 2 MB
    float* scale = (float*)((char*)d_ws + (size_t)D_OUT * D_IN * 2); // 4 KB

    dora_prep<<<D_OUT, 256, 0, stream>>>(w, a_w, b_w, mag, wb, scale);

    const int grid = (M_TOT / BM) * (D_OUT / BN);  // 2048
    dora_gemm<<<grid, 256, 0, stream>>>(x, wb, scale, out);
}

// Round 4
// 352.459 us; speedup vs baseline: 1.1012x; 1.1012x over previous
//
#include <hip/hip_runtime.h>
#include <hip/hip_bf16.h>

// out[b,s,o] = scale[o] * dot(x[b,s,:], w_eff[o,:])
//   w_eff = weight + 2.0*(b_w @ a_w);  scale[o] = magnitude[o]/||w_eff[o,:]||
// Phase 1: prep builds w_eff bf16 + scale fp32                 (~10us)
// Phase 2: FUSED GEMM, m97 structure (single-buffer LDS, 2 barriers,
//          ALL staging via global_load_lds):
//            A staged as fp32 (no conversion on staging path), source-XOR-
//            swizzled so fragment ds_reads are bank-spread; fp32->bf16
//            conversion happens at fragment-read (VALU, overlappable).
//            B = w_eff bf16, identical to the known-good round-0 path.
// No x_to_bf16 pass (192 MB of HBM traffic + one launch eliminated).

typedef __bf16 bf16x8 __attribute__((ext_vector_type(8)));
typedef float  f32x4  __attribute__((ext_vector_type(4)));

#define D_IN  1024
#define D_OUT 1024
#define M_TOT 32768
#define BM 128
#define BN 128
#define BK 32

__device__ __forceinline__ void gl_lds16(const __bf16* g, __bf16* l) {
    // HBM -> LDS DMA, 16B/lane; LDS dest = wave-uniform base + lane*16.
    __builtin_amdgcn_global_load_lds(
        (const __attribute__((address_space(1))) void*)g,
        (__attribute__((address_space(3))) void*)l,
        16, 0, 0);
}

__device__ __forceinline__ void gl_lds16f(const float* g, float* l) {
    __builtin_amdgcn_global_load_lds(
        (const __attribute__((address_space(1))) void*)g,
        (__attribute__((address_space(3))) void*)l,
        16, 0, 0);
}

__global__ void dora_prep(const float* __restrict__ w,
                          const float* __restrict__ a_w,
                          const float* __restrict__ b_w,
                          const float* __restrict__ mag,
                          __bf16* __restrict__ wb,
                          float* __restrict__ scale) {
    const int o = blockIdx.x;
    const int t = threadIdx.x;

    float bw[16];
#pragma unroll
    for (int r = 0; r < 16; ++r) bw[r] = b_w[o * 16 + r];

    float ss = 0.f;
#pragma unroll
    for (int i = 0; i < 4; ++i) {
        const int k = t + i * 256;
        float dot = 0.f;
#pragma unroll
        for (int r = 0; r < 16; ++r) dot = fmaf(bw[r], a_w[r * D_IN + k], dot);
        const float acc = fmaf(2.0f, dot, w[o * D_IN + k]);
        wb[o * D_IN + k] = (__bf16)acc;
        ss = fmaf(acc, acc, ss);
    }
#pragma unroll
    for (int off = 32; off; off >>= 1) ss += __shfl_down(ss, off, 64);
    __shared__ float wsum[4];
    if ((t & 63) == 0) wsum[t >> 6] = ss;
    __syncthreads();
    if (t == 0) {
        const float tot = wsum[0] + wsum[1] + wsum[2] + wsum[3];
        scale[o] = mag[o] / sqrtf(tot);
    }
}

__global__ __launch_bounds__(256) void dora_gemm(const float* __restrict__ x,
                                                 const __bf16* __restrict__ wb,
                                                 const float* __restrict__ scale,
                                                 float* __restrict__ out) {
    // Single-buffered tiles (m97 2-barrier structure).
    // Asf: fp32 [128][32], 16 KB, 16B-chunk swizzled: logical (row,c) lives at
    //      chunk row*8 + (c ^ (row&7)).  (LDS itself is written linearly by
    //      gl_lds; the PERMUTATION is done on the per-lane global source.)
    // Bs : bf16 [128][32], 8 KB, linear row-major (round-0 verified path).
    __shared__ float  Asf[BM * BK];
    __shared__ __bf16 Bs[BN * BK];

    const int bx = blockIdx.x;
    // XCD-aware swizzle: 8 bn-siblings sharing one A panel land on ONE XCD's
    // L2 at the same time -> fp32 A re-reads are L2 hits.
    const int xcd = bx & 7;
    const int l   = bx >> 3;
    const int bm  = (xcd * 32 + (l >> 3)) * BM;
    const int bn  = (l & 7) * BN;

    const int t    = threadIdx.x;
    const int lane = t & 63;
    const int wave = t >> 6;
    const int wm = (wave & 1) * 64;
    const int wn = (wave >> 1) * 64;
    const int lm = lane & 15;
    const int lq = lane >> 4;

    // ---- A staging (fp32, source-swizzled, 4 gl_lds per wave) ----
    // Instr q of wave w covers physical 16B chunks p = w*256 + q*64 + lane
    // (LDS dest is wave-uniform base + lane*16).  With Asf as [row][8 chunks]:
    // row = p>>3 = w*32 + q*8 + (lane>>3), phys_c = lane&7, and the logical
    // chunk stored there must be phys_c ^ (row&7) = (lane&7) ^ (lane>>3).
    const int lr = lane >> 3;            // row within the 8-row group
    const int lc = (lane & 7) ^ lr;      // logical chunk this lane must fetch
    const float* ag0 = x + (size_t)(bm + wave * 32 +  0 + lr) * D_IN + lc * 4;
    const float* ag1 = x + (size_t)(bm + wave * 32 +  8 + lr) * D_IN + lc * 4;
    const float* ag2 = x + (size_t)(bm + wave * 32 + 16 + lr) * D_IN + lc * 4;
    const float* ag3 = x + (size_t)(bm + wave * 32 + 24 + lr) * D_IN + lc * 4;
    float* al0 = Asf + wave * 1024;
    float* al1 = Asf + wave * 1024 + 256;
    float* al2 = Asf + wave * 1024 + 512;
    float* al3 = Asf + wave * 1024 + 768;

    // ---- B staging (bf16, linear, 2 gl_lds per wave; round-0 pattern) ----
    const int srow0 = wave * 32 + (lane >> 2);
    const int scol  = (lane & 3) * 8;
    const __bf16* bg0 = wb + (size_t)(bn + srow0) * D_IN + scol;
    const __bf16* bg1 = bg0 + 16 * D_IN;
    __bf16* bl0 = Bs + wave * 1024;
    __bf16* bl1 = Bs + wave * 1024 + 512;

    f32x4 acc[4][4] = {};

    for (int kk = 0; kk < D_IN; kk += BK) {
        gl_lds16f(ag0 + kk, al0);
        gl_lds16f(ag1 + kk, al1);
        gl_lds16f(ag2 + kk, al2);
        gl_lds16f(ag3 + kk, al3);
        gl_lds16(bg0 + kk, bl0);
        gl_lds16(bg1 + kk, bl1);
        __syncthreads();   // drains vmcnt: both tiles resident

        bf16x8 af[4], bfr[4];
#pragma unroll
        for (int i = 0; i < 4; ++i) {
            const int r  = wm + i * 16 + lm;
            const int sw = r & 7;
            // logical chunks {2lq, 2lq+1} of row r, at swizzled slots
            const f32x4 lo = *(const f32x4*)(Asf + r * BK + (((lq * 2)     ^ sw) * 4));
            const f32x4 hi = *(const f32x4*)(Asf + r * BK + (((lq * 2 + 1) ^ sw) * 4));
            bf16x8 a8 = { (__bf16)lo.x, (__bf16)lo.y, (__bf16)lo.z, (__bf16)lo.w,
                          (__bf16)hi.x, (__bf16)hi.y, (__bf16)hi.z, (__bf16)hi.w };
            af[i] = a8;
        }
#pragma unroll
        for (int j = 0; j < 4; ++j)
            bfr[j] = *(const bf16x8*)(&Bs[(wn + j * 16 + lm) * BK + lq * 8]);

#pragma unroll
        for (int i = 0; i < 4; ++i)
#pragma unroll
            for (int j = 0; j < 4; ++j)
                acc[i][j] = __builtin_amdgcn_mfma_f32_16x16x32_bf16(af[i], bfr[j], acc[i][j], 0, 0, 0);
        __syncthreads();   // all reads done before next-iter overwrite
    }

    // Epilogue: C/D map col = lane&15 (n), row = (lane>>4)*4 + reg (m)
#pragma unroll
    for (int j = 0; j < 4; ++j) {
        const int n = bn + wn + j * 16 + lm;
        const float sc = scale[n];
#pragma unroll
        for (int i = 0; i < 4; ++i) {
            const int m = bm + wm + i * 16 + lq * 4;
#pragma unroll
            for (int r = 0; r < 4; ++r) {
                out[(size_t)(m + r) * D_OUT + n] = acc[i][j][r] * sc;
            }
        }
    }
}

extern "C" void kernel_launch(void* const* d_in, const int* in_sizes, int n_in,
                              void* d_out, int out_size, void* d_ws, size_t ws_size,
                              hipStream_t stream) {
    const float* x    = (const float*)d_in[0];   // [4,8192,1024] fp32
    const float* w    = (const float*)d_in[1];   // [1024,1024]
    const float* a_w  = (const float*)d_in[2];   // [16,1024]
    const float* b_w  = (const float*)d_in[3];   // [1024,16]
    const float* mag  = (const float*)d_in[4];   // [1,1024]
    float* out = (float*)d_out;                  // [4,8192,1024] fp32

    __bf16* wb   = (__bf16*)d_ws;                                    // 2 MB
    float* scale = (float*)((char*)d_ws + (size_t)D_OUT * D_IN * 2); // 4 KB

    dora_prep<<<D_OUT, 256, 0, stream>>>(w, a_w, b_w, mag, wb, scale);

    const int grid = (M_TOT / BM) * (D_OUT / BN);  // 2048
    dora_gemm<<<grid, 256, 0, stream>>>(x, wb, scale, out);
}